// Round 20
// baseline (77.995 us; speedup 1.0000x reference)
//
#include <hip/hip_runtime.h>

#define NB 16
#define TT 6000
#define HH 256
#define CC 105
#define MIN_GAP_ 19
#define REF_GAP_ 9

using short8  = __attribute__((ext_vector_type(8))) short;
using short4v = __attribute__((ext_vector_type(4))) short;
using f32x4   = __attribute__((ext_vector_type(4))) float;

static __device__ __forceinline__ short f2bf(float x) {
  unsigned u = __builtin_bit_cast(unsigned, x);
  unsigned r = (u + 0x7FFFu + ((u >> 16) & 1u)) >> 16;   // RNE
  return (short)r;
}

// ---- GEMM (R15 fused config), bS trimmed to 104 rows = 53,248 B ->
// ---- 3 blocks/CU (159.7 KB of 160): all 750 blocks co-resident, no tail
// ---- round, 24 waves/CU. B-row reads clamped to 103 (pad rows removed;
// ---- affected lanes were always discarded by the c < CC-1 store guard).
#define NGRID 750

__global__ __launch_bounds__(512, 6) void gemm_mfma(
    const float* __restrict__ feat, const float* __restrict__ W,
    const float* __restrict__ bias,
    float* __restrict__ out0, float* __restrict__ out1) {
  __shared__ __align__(16) unsigned short bS[104 * 256];   // 53,248 B
  const int tid  = threadIdx.x;
  const int wv   = tid >> 6;
  const int lane = tid & 63;
  const int rl   = lane & 15;
  const int kg   = lane >> 4;
  const int row  = blockIdx.x * 128 + wv * 16 + rl;
  const float* frow = feat + (size_t)row * HH;

  // ---- issue ALL 16 A loads first (256B/lane in flight) ----
  float4 areg[16];
#pragma unroll
  for (int ks = 0; ks < 8; ks++) {
    const int kk = ks * 32 + kg * 8;
    areg[2 * ks]     = *reinterpret_cast<const float4*>(frow + kk);
    areg[2 * ks + 1] = *reinterpret_cast<const float4*>(frow + kk + 4);
  }

  // ---- stage B: W rows 1..104 -> bf16 -> swizzled LDS (104 rows) ----
#pragma unroll
  for (int i = 0; i < 7; i++) {
    const int c16 = i * 512 + tid;          // valid < 3328
    if (c16 < 3328) {
      const int brow = c16 >> 5;
      const int boff = (c16 & 31) << 4;
      char* dst = (char*)bS + (brow << 9) + (boff ^ ((brow & 7) << 4));
      const float* src = W + ((size_t)(brow + 1) << 8) + ((c16 & 31) << 3);
      const float4 f0 = *reinterpret_cast<const float4*>(src);
      const float4 f1 = *reinterpret_cast<const float4*>(src + 4);
      short8 bv;
      bv[0] = f2bf(f0.x); bv[1] = f2bf(f0.y); bv[2] = f2bf(f0.z); bv[3] = f2bf(f0.w);
      bv[4] = f2bf(f1.x); bv[5] = f2bf(f1.y); bv[6] = f2bf(f1.z); bv[7] = f2bf(f1.w);
      *reinterpret_cast<short8*>(dst) = bv;
    }
  }
  __syncthreads();

  // B-row byte offsets, clamped to row 103 (lanes with c>=104 are discarded
  // at the store guard; clamp keeps their reads in-bounds)
  int browoff[7];
#pragma unroll
  for (int n = 0; n < 7; n++) {
    const int r = n * 16 + rl;
    browoff[n] = ((r < 104) ? r : 103) << 9;
  }

  const int xr = (rl & 7) << 4;
  f32x4 acc[7];
#pragma unroll
  for (int n = 0; n < 7; n++) acc[n] = (f32x4){0.f, 0.f, 0.f, 0.f};
  float c0 = 0.f;

#pragma unroll
  for (int ks = 0; ks < 8; ks++) {
    const int kk = ks * 32 + kg * 8;
    const float4 a0 = areg[2 * ks];
    const float4 a1 = areg[2 * ks + 1];
    const float4 w0a = *reinterpret_cast<const float4*>(W + kk);
    const float4 w0b = *reinterpret_cast<const float4*>(W + kk + 4);
    c0 = fmaf(a0.x, w0a.x, c0); c0 = fmaf(a0.y, w0a.y, c0);
    c0 = fmaf(a0.z, w0a.z, c0); c0 = fmaf(a0.w, w0a.w, c0);
    c0 = fmaf(a1.x, w0b.x, c0); c0 = fmaf(a1.y, w0b.y, c0);
    c0 = fmaf(a1.z, w0b.z, c0); c0 = fmaf(a1.w, w0b.w, c0);

    short8 av;
    av[0] = f2bf(a0.x); av[1] = f2bf(a0.y); av[2] = f2bf(a0.z); av[3] = f2bf(a0.w);
    av[4] = f2bf(a1.x); av[5] = f2bf(a1.y); av[6] = f2bf(a1.z); av[7] = f2bf(a1.w);

    const int boff = (ks * 64 + kg * 16) ^ xr;
    const char* bbase = (const char*)bS + boff;
    short8 bv[7];
#pragma unroll
    for (int n = 0; n < 7; n++)
      bv[n] = *reinterpret_cast<const short8*>(bbase + browoff[n]);
#pragma unroll
    for (int n = 0; n < 7; n++)
      acc[n] = __builtin_amdgcn_mfma_f32_16x16x32_bf16(av, bv[n], acc[n], 0, 0, 0);
  }

  c0 += __shfl_xor(c0, 16);
  c0 += __shfl_xor(c0, 32);
  if (kg == 0) out0[row] = fminf(fmaxf(c0 + bias[0], -16.f), 16.f);

  // D layout: col = lane&15, row = (lane>>4)*4 + reg  [m89]
  const int rbase = blockIdx.x * 128 + wv * 16 + kg * 4;
#pragma unroll
  for (int n = 0; n < 7; n++) {
    const int c = n * 16 + rl;
    if (c < CC - 1) {
      const float bb = bias[c + 1];
#pragma unroll
      for (int r = 0; r < 4; r++)
        out1[(size_t)(rbase + r) * (CC - 1) + c] = acc[n][r] + bb;
    }
  }
}

// ---- phase (R18 version, unchanged): 1024 threads, int4 spec/replay ----
#define NW 192
#define NW_LAST 187
#define CHUNK 32
#define NCLS 19
#define MAXRUNS 3072
#define MAXCH 96

__global__ __launch_bounds__(1024) void phase_kernel(
    const float* __restrict__ bd_logits,
    const int* __restrict__ word_bd,
    const float* __restrict__ non_padding,
    float* __restrict__ out2) {
  __shared__ __align__(16) float lbuf[TT];
  __shared__ unsigned char wbuf[TT];
  __shared__ __align__(16) int res[TT];
  __shared__ unsigned bdbits[NW];
  __shared__ __align__(16) int runIdx[MAXRUNS];
  __shared__ int outLast[MAXCH][NCLS + 1];
  __shared__ int chP0[MAXCH];
  __shared__ int inL[MAXCH + 1];
  __shared__ int wsum[16];
  __shared__ int wbase[16];
  __shared__ int L_sh, nruns_sh;

  const int b = blockIdx.x;
  const int tid = threadIdx.x;
  const int lane = tid & 63;
  const int wid = tid >> 6;
  if (tid == 0) L_sh = 0;
  __syncthreads();

  int cnt_np = 0;
#pragma unroll
  for (int k = 0; k < 6; k++) {
    const int j = k * 1024 + tid;
    bool pred = false;
    if (j < TT) {
      const float l = bd_logits[(size_t)b * TT + j];
      lbuf[j] = l;
      pred = l > 0.f;
      wbuf[j] = (unsigned char)word_bd[(size_t)b * TT + j];
      res[j] = 0;
      cnt_np += (non_padding[(size_t)b * TT + j] != 0.f) ? 1 : 0;
    }
    const unsigned long long m = __ballot(pred);
    if (lane == 0) {
      const int w0 = (k * 1024 + (tid & ~63)) >> 5;
      bdbits[w0]     = (unsigned)m;
      bdbits[w0 + 1] = (unsigned)(m >> 32);
    }
  }
#pragma unroll
  for (int off = 32; off; off >>= 1) cnt_np += __shfl_xor(cnt_np, off);
  if (lane == 0) atomicAdd(&L_sh, cnt_np);
  __syncthreads();

  int cnt = 0;
  unsigned ends = 0;
  if (tid < NW) {
    const unsigned cur = bdbits[tid];
    const unsigned pb = tid ? (bdbits[tid - 1] >> 31) : 0u;
    ends = ((cur << 1) | pb) & ~cur;
    if (tid == NW_LAST) ends &= 0xFFFFu;
    cnt = __popc(ends);
  }
  int v = cnt;
#pragma unroll
  for (int off = 1; off < 64; off <<= 1) {
    const int t = __shfl_up(v, off);
    if (lane >= off) v += t;
  }
  if (lane == 63) wsum[wid] = v;
  __syncthreads();
  if (tid == 0) {
    int s = 0;
#pragma unroll
    for (int w = 0; w < 16; w++) { wbase[w] = s; s += wsum[w]; }
    nruns_sh = s;
  }
  __syncthreads();
  int slot = wbase[wid] + v - cnt;

  for (int p = nruns_sh + tid; p < nruns_sh + 40 && p < MAXRUNS; p += 1024)
    runIdx[p] = 0;

  if (ends) {
    unsigned m = ends;
    while (m) {
      const int bit = __builtin_ctz(m);
      m &= m - 1;
      const int e = tid * 32 + bit;
      const int eb = e - 1;
      int w = eb >> 5;
      const int bb = eb & 31;
      const unsigned z = bdbits[w] << (31 - bb);
      const unsigned nz = ~z;
      int run = nz ? __builtin_clz(nz) : 32;
      if (run == bb + 1) {
        while (w > 0) {
          w--;
          const unsigned nx = ~bdbits[w];
          const int t2 = nx ? __builtin_clz(nx) : 32;
          run += t2;
          if (t2 < 32) break;
        }
      }
      const int s = e - run;
      float mv = lbuf[s];
      int mi = s;
      for (int i = s + 1; i < e; i++) {
        const float val = lbuf[i];
        if (val > mv) { mv = val; mi = i; }
      }
      runIdx[slot++] = mi;
    }
  }
  __syncthreads();

  const int n = nruns_sh;
  const int nch = (n + CHUNK - 1) / CHUNK;
  for (int f = tid; f < nch * NCLS; f += 1024) {
    const int ch = f / NCLS;
    const int cls = f - ch * NCLS;
    const int s = ch * CHUNK;
    const int m = (n - s < CHUNK) ? (n - s) : CHUNK;
    int vals[CHUNK];
#pragma unroll
    for (int q = 0; q < CHUNK / 4; q++) {
      const int4 v4 = *reinterpret_cast<const int4*>(&runIdx[s + q * 4]);
      vals[q * 4 + 0] = v4.x; vals[q * 4 + 1] = v4.y;
      vals[q * 4 + 2] = v4.z; vals[q * 4 + 3] = v4.w;
    }
    const int p0 = vals[0];
    if (cls == NCLS - 1) chP0[ch] = p0;
    int last = (cls < 18) ? (p0 - 18 + cls) : -1;
#pragma unroll
    for (int i = 0; i < CHUNK; i++) {
      if (i >= m) break;
      int bd = vals[i];
      if (last > 0 && bd - last < MIN_GAP_) {
        const int sum = bd + last;
        const int h = sum >> 1;
        bd = (sum & 1) ? (h + (h & 1)) : h;   // round half to even
      }
      last = bd;
    }
    outLast[ch][cls] = last;
  }
  __syncthreads();

  if (wid == 0) {
    int q = -1;
    int row = (lane < NCLS && nch > 0) ? outLast[0][lane] : -1;
    for (int ch = 0; ch < nch; ch++) {
      const int rown = (lane < NCLS && ch + 1 < nch) ? outLast[ch + 1][lane] : -1;
      const int p0 = chP0[ch];
      const int cls = (q > 0 && p0 - q < MIN_GAP_) ? (q - (p0 - 18)) : (NCLS - 1);
      if (lane == 0) inL[ch] = q;
      q = __shfl(row, cls);
      row = rown;
    }
    if (lane == 0) inL[nch] = q;
  }
  __syncthreads();

  for (int ch = tid; ch < nch; ch += 1024) {
    const int s = ch * CHUNK;
    const int m = (n - s < CHUNK) ? (n - s) : CHUNK;
    int vals[CHUNK];
#pragma unroll
    for (int q = 0; q < CHUNK / 4; q++) {
      const int4 v4 = *reinterpret_cast<const int4*>(&runIdx[s + q * 4]);
      vals[q * 4 + 0] = v4.x; vals[q * 4 + 1] = v4.y;
      vals[q * 4 + 2] = v4.z; vals[q * 4 + 3] = v4.w;
    }
    const int qin = inL[ch];
    const int qout = inL[ch + 1];
    if (qin >= 0 && qin != qout) res[qin] = 1;
    int last = qin;
#pragma unroll
    for (int i = 0; i < CHUNK; i++) {
      if (i >= m) break;
      int bd = vals[i];
      if (last > 0 && bd - last < MIN_GAP_) {
        const int sum = bd + last;
        const int h = sum >> 1;
        bd = (sum & 1) ? (h + (h & 1)) : h;
        if (last != qout) res[last] = 0;
      }
      if (bd != qout) res[bd] = 1;
      last = bd;
    }
  }
  if (tid == 0 && n > 0) res[inL[nch]] = 1;
  __syncthreads();

  for (int j = tid; j < TT; j += 1024) {
    if (wbuf[j] != 1) continue;
    const int lo = (j - REF_GAP_ < 0) ? 0 : j - REF_GAP_;
    const int hi = (j + REF_GAP_ - 1 > TT - 1) ? TT - 1 : j + REF_GAP_ - 1;
    int seg = 0;
    for (int w = lo; w <= hi; w++) seg += res[w];
    if (seg == 0) {
      res[j] = 1;
    } else if (seg == 1) {
      if (res[j] != 1) {
        for (int w = lo; w <= hi; w++) res[w] = (int)wbuf[w];
      }
    } else {
      int zidx = -1;
      for (int k = 1; k <= REF_GAP_; k++) {
        const int li = (j - k < 0) ? 0 : j - k;
        const int ri = (j + k > TT - 1) ? TT - 1 : j + k;
        if (res[li] == 1 && wbuf[li] != 1) { zidx = li; break; }
        if (res[ri] == 1 && wbuf[ri] != 1) { zidx = ri; break; }
      }
      if (zidx >= 0) res[zidx] = 0;
      res[j] = 1;
    }
  }
  __syncthreads();

  const int L = L_sh;
  for (int t4 = tid; t4 < TT / 4; t4 += 1024) {
    const int4 r4 = *reinterpret_cast<const int4*>(&res[t4 * 4]);
    const int t = t4 * 4;
    float4 o;
    o.x = (t + 0 >= 1 && t + 0 < L - 1) ? (float)r4.x : 0.f;
    o.y = (t + 1 >= 1 && t + 1 < L - 1) ? (float)r4.y : 0.f;
    o.z = (t + 2 >= 1 && t + 2 < L - 1) ? (float)r4.z : 0.f;
    o.w = (t + 3 >= 1 && t + 3 < L - 1) ? (float)r4.w : 0.f;
    *reinterpret_cast<float4*>(&out2[(size_t)b * TT + t]) = o;
  }
}

extern "C" void kernel_launch(void* const* d_in, const int* in_sizes, int n_in,
                              void* d_out, int out_size, void* d_ws, size_t ws_size,
                              hipStream_t stream) {
  const float* feat        = (const float*)d_in[0];
  const int*   word_bd     = (const int*)d_in[1];
  const float* non_padding = (const float*)d_in[2];
  const float* W           = (const float*)d_in[3];
  const float* bias        = (const float*)d_in[4];

  float* out  = (float*)d_out;
  float* out0 = out;
  float* out1 = out + (size_t)NB * TT;
  float* out2 = out + (size_t)NB * TT + (size_t)NB * TT * (CC - 1);

  hipLaunchKernelGGL(gemm_mfma, dim3(NGRID), dim3(512), 0, stream,
                     feat, W, bias, out0, out1);
  hipLaunchKernelGGL(phase_kernel, dim3(NB), dim3(1024), 0, stream,
                     out0, word_bd, non_padding, out2);
}

// Round 21
// 59.959 us; speedup vs baseline: 1.3008x; 1.3008x over previous
//
#include <hip/hip_runtime.h>

#define NB 16
#define TT 6000
#define HH 256
#define CC 105
#define MIN_GAP_ 19
#define REF_GAP_ 9

using short8  = __attribute__((ext_vector_type(8))) short;
using short4v = __attribute__((ext_vector_type(4))) short;
using f32x4   = __attribute__((ext_vector_type(4))) float;

static __device__ __forceinline__ short f2bf(float x) {
  unsigned u = __builtin_bit_cast(unsigned, x);
  unsigned r = (u + 0x7FFFu + ((u >> 16) & 1u)) >> 16;   // RNE
  return (short)r;
}

// ---- GEMM (R19 best config): fused W-convert, B in LDS (56KB swizzled,
// ---- 2 blocks/CU, VGPR 128 cap -> 16-deep A MLP intact), LDS-tile float4
// ---- epilogue (clean 41MB write traffic).
#define NGRID 750
#define TPAD 108

__global__ __launch_bounds__(512, 4) void gemm_mfma(
    const float* __restrict__ feat, const float* __restrict__ W,
    const float* __restrict__ bias,
    float* __restrict__ out0, float* __restrict__ out1) {
  __shared__ __align__(16) unsigned short bS[112 * 256];   // 56 KB
  const int tid  = threadIdx.x;
  const int wv   = tid >> 6;
  const int lane = tid & 63;
  const int rl   = lane & 15;
  const int kg   = lane >> 4;
  const int row  = blockIdx.x * 128 + wv * 16 + rl;
  const float* frow = feat + (size_t)row * HH;

  float4 areg[16];
#pragma unroll
  for (int ks = 0; ks < 8; ks++) {
    const int kk = ks * 32 + kg * 8;
    areg[2 * ks]     = *reinterpret_cast<const float4*>(frow + kk);
    areg[2 * ks + 1] = *reinterpret_cast<const float4*>(frow + kk + 4);
  }

#pragma unroll
  for (int i = 0; i < 7; i++) {
    const int c16 = i * 512 + tid;
    const int brow = c16 >> 5;
    const int boff = (c16 & 31) << 4;
    char* dst = (char*)bS + (brow << 9) + (boff ^ ((brow & 7) << 4));
    if (c16 < 3328) {
      const float* src = W + ((size_t)(brow + 1) << 8) + ((c16 & 31) << 3);
      const float4 f0 = *reinterpret_cast<const float4*>(src);
      const float4 f1 = *reinterpret_cast<const float4*>(src + 4);
      short8 bv;
      bv[0] = f2bf(f0.x); bv[1] = f2bf(f0.y); bv[2] = f2bf(f0.z); bv[3] = f2bf(f0.w);
      bv[4] = f2bf(f1.x); bv[5] = f2bf(f1.y); bv[6] = f2bf(f1.z); bv[7] = f2bf(f1.w);
      *reinterpret_cast<short8*>(dst) = bv;
    } else {
      *reinterpret_cast<short8*>(dst) = (short8){0, 0, 0, 0, 0, 0, 0, 0};
    }
  }
  __syncthreads();

  const int xr = (rl & 7) << 4;
  f32x4 acc[7];
#pragma unroll
  for (int n = 0; n < 7; n++) acc[n] = (f32x4){0.f, 0.f, 0.f, 0.f};
  float c0 = 0.f;

#pragma unroll
  for (int ks = 0; ks < 8; ks++) {
    const int kk = ks * 32 + kg * 8;
    const float4 a0 = areg[2 * ks];
    const float4 a1 = areg[2 * ks + 1];
    const float4 w0a = *reinterpret_cast<const float4*>(W + kk);
    const float4 w0b = *reinterpret_cast<const float4*>(W + kk + 4);
    c0 = fmaf(a0.x, w0a.x, c0); c0 = fmaf(a0.y, w0a.y, c0);
    c0 = fmaf(a0.z, w0a.z, c0); c0 = fmaf(a0.w, w0a.w, c0);
    c0 = fmaf(a1.x, w0b.x, c0); c0 = fmaf(a1.y, w0b.y, c0);
    c0 = fmaf(a1.z, w0b.z, c0); c0 = fmaf(a1.w, w0b.w, c0);

    short8 av;
    av[0] = f2bf(a0.x); av[1] = f2bf(a0.y); av[2] = f2bf(a0.z); av[3] = f2bf(a0.w);
    av[4] = f2bf(a1.x); av[5] = f2bf(a1.y); av[6] = f2bf(a1.z); av[7] = f2bf(a1.w);

    const int boff = (ks * 64 + kg * 16) ^ xr;
    const char* bbase = (const char*)bS + boff;
    short8 bv[7];
#pragma unroll
    for (int n = 0; n < 7; n++)
      bv[n] = *reinterpret_cast<const short8*>(bbase + ((n * 16 + rl) << 9));
#pragma unroll
    for (int n = 0; n < 7; n++)
      acc[n] = __builtin_amdgcn_mfma_f32_16x16x32_bf16(av, bv[n], acc[n], 0, 0, 0);
  }

  c0 += __shfl_xor(c0, 16);
  c0 += __shfl_xor(c0, 32);
  if (kg == 0) out0[row] = fminf(fmaxf(c0 + bias[0], -16.f), 16.f);

  // ---- epilogue: acc -> LDS f32 tile (pad 108) -> contiguous float4 out1 ----
  __syncthreads();                       // bS dead: safe to reuse as tile
  float* tile = (float*)bS;              // [128][TPAD]
  const int trow0 = wv * 16 + kg * 4;
#pragma unroll
  for (int n = 0; n < 7; n++) {
    const int c = n * 16 + rl;
    if (c < CC - 1) {
      const float bb = bias[c + 1];
#pragma unroll
      for (int r = 0; r < 4; r++)
        tile[(trow0 + r) * TPAD + c] = acc[n][r] + bb;
    }
  }
  __syncthreads();

  float* oblk = out1 + (size_t)(blockIdx.x * 128) * (CC - 1);
  for (int t = tid; t < 128 * 26; t += 512) {
    const int r = t / 26;
    const int q = t - r * 26;
    const float4 v = *reinterpret_cast<const float4*>(&tile[r * TPAD + q * 4]);
    *reinterpret_cast<float4*>(&oblk[r * (CC - 1) + q * 4]) = v;
  }
}

// ---- phase (R18 version): 1024 threads, int4 spec/replay ----
#define NW 192
#define NW_LAST 187
#define CHUNK 32
#define NCLS 19
#define MAXRUNS 3072
#define MAXCH 96

__global__ __launch_bounds__(1024) void phase_kernel(
    const float* __restrict__ bd_logits,
    const int* __restrict__ word_bd,
    const float* __restrict__ non_padding,
    float* __restrict__ out2) {
  __shared__ __align__(16) float lbuf[TT];
  __shared__ unsigned char wbuf[TT];
  __shared__ __align__(16) int res[TT];
  __shared__ unsigned bdbits[NW];
  __shared__ __align__(16) int runIdx[MAXRUNS];
  __shared__ int outLast[MAXCH][NCLS + 1];
  __shared__ int chP0[MAXCH];
  __shared__ int inL[MAXCH + 1];
  __shared__ int wsum[16];
  __shared__ int wbase[16];
  __shared__ int L_sh, nruns_sh;

  const int b = blockIdx.x;
  const int tid = threadIdx.x;
  const int lane = tid & 63;
  const int wid = tid >> 6;
  if (tid == 0) L_sh = 0;
  __syncthreads();

  int cnt_np = 0;
#pragma unroll
  for (int k = 0; k < 6; k++) {
    const int j = k * 1024 + tid;
    bool pred = false;
    if (j < TT) {
      const float l = bd_logits[(size_t)b * TT + j];
      lbuf[j] = l;
      pred = l > 0.f;
      wbuf[j] = (unsigned char)word_bd[(size_t)b * TT + j];
      res[j] = 0;
      cnt_np += (non_padding[(size_t)b * TT + j] != 0.f) ? 1 : 0;
    }
    const unsigned long long m = __ballot(pred);
    if (lane == 0) {
      const int w0 = (k * 1024 + (tid & ~63)) >> 5;
      bdbits[w0]     = (unsigned)m;
      bdbits[w0 + 1] = (unsigned)(m >> 32);
    }
  }
#pragma unroll
  for (int off = 32; off; off >>= 1) cnt_np += __shfl_xor(cnt_np, off);
  if (lane == 0) atomicAdd(&L_sh, cnt_np);
  __syncthreads();

  int cnt = 0;
  unsigned ends = 0;
  if (tid < NW) {
    const unsigned cur = bdbits[tid];
    const unsigned pb = tid ? (bdbits[tid - 1] >> 31) : 0u;
    ends = ((cur << 1) | pb) & ~cur;
    if (tid == NW_LAST) ends &= 0xFFFFu;
    cnt = __popc(ends);
  }
  int v = cnt;
#pragma unroll
  for (int off = 1; off < 64; off <<= 1) {
    const int t = __shfl_up(v, off);
    if (lane >= off) v += t;
  }
  if (lane == 63) wsum[wid] = v;
  __syncthreads();
  if (tid == 0) {
    int s = 0;
#pragma unroll
    for (int w = 0; w < 16; w++) { wbase[w] = s; s += wsum[w]; }
    nruns_sh = s;
  }
  __syncthreads();
  int slot = wbase[wid] + v - cnt;

  for (int p = nruns_sh + tid; p < nruns_sh + 40 && p < MAXRUNS; p += 1024)
    runIdx[p] = 0;

  if (ends) {
    unsigned m = ends;
    while (m) {
      const int bit = __builtin_ctz(m);
      m &= m - 1;
      const int e = tid * 32 + bit;
      const int eb = e - 1;
      int w = eb >> 5;
      const int bb = eb & 31;
      const unsigned z = bdbits[w] << (31 - bb);
      const unsigned nz = ~z;
      int run = nz ? __builtin_clz(nz) : 32;
      if (run == bb + 1) {
        while (w > 0) {
          w--;
          const unsigned nx = ~bdbits[w];
          const int t2 = nx ? __builtin_clz(nx) : 32;
          run += t2;
          if (t2 < 32) break;
        }
      }
      const int s = e - run;
      float mv = lbuf[s];
      int mi = s;
      for (int i = s + 1; i < e; i++) {
        const float val = lbuf[i];
        if (val > mv) { mv = val; mi = i; }
      }
      runIdx[slot++] = mi;
    }
  }
  __syncthreads();

  const int n = nruns_sh;
  const int nch = (n + CHUNK - 1) / CHUNK;
  for (int f = tid; f < nch * NCLS; f += 1024) {
    const int ch = f / NCLS;
    const int cls = f - ch * NCLS;
    const int s = ch * CHUNK;
    const int m = (n - s < CHUNK) ? (n - s) : CHUNK;
    int vals[CHUNK];
#pragma unroll
    for (int q = 0; q < CHUNK / 4; q++) {
      const int4 v4 = *reinterpret_cast<const int4*>(&runIdx[s + q * 4]);
      vals[q * 4 + 0] = v4.x; vals[q * 4 + 1] = v4.y;
      vals[q * 4 + 2] = v4.z; vals[q * 4 + 3] = v4.w;
    }
    const int p0 = vals[0];
    if (cls == NCLS - 1) chP0[ch] = p0;
    int last = (cls < 18) ? (p0 - 18 + cls) : -1;
#pragma unroll
    for (int i = 0; i < CHUNK; i++) {
      if (i >= m) break;
      int bd = vals[i];
      if (last > 0 && bd - last < MIN_GAP_) {
        const int sum = bd + last;
        const int h = sum >> 1;
        bd = (sum & 1) ? (h + (h & 1)) : h;   // round half to even
      }
      last = bd;
    }
    outLast[ch][cls] = last;
  }
  __syncthreads();

  if (wid == 0) {
    int q = -1;
    int row = (lane < NCLS && nch > 0) ? outLast[0][lane] : -1;
    for (int ch = 0; ch < nch; ch++) {
      const int rown = (lane < NCLS && ch + 1 < nch) ? outLast[ch + 1][lane] : -1;
      const int p0 = chP0[ch];
      const int cls = (q > 0 && p0 - q < MIN_GAP_) ? (q - (p0 - 18)) : (NCLS - 1);
      if (lane == 0) inL[ch] = q;
      q = __shfl(row, cls);
      row = rown;
    }
    if (lane == 0) inL[nch] = q;
  }
  __syncthreads();

  for (int ch = tid; ch < nch; ch += 1024) {
    const int s = ch * CHUNK;
    const int m = (n - s < CHUNK) ? (n - s) : CHUNK;
    int vals[CHUNK];
#pragma unroll
    for (int q = 0; q < CHUNK / 4; q++) {
      const int4 v4 = *reinterpret_cast<const int4*>(&runIdx[s + q * 4]);
      vals[q * 4 + 0] = v4.x; vals[q * 4 + 1] = v4.y;
      vals[q * 4 + 2] = v4.z; vals[q * 4 + 3] = v4.w;
    }
    const int qin = inL[ch];
    const int qout = inL[ch + 1];
    if (qin >= 0 && qin != qout) res[qin] = 1;
    int last = qin;
#pragma unroll
    for (int i = 0; i < CHUNK; i++) {
      if (i >= m) break;
      int bd = vals[i];
      if (last > 0 && bd - last < MIN_GAP_) {
        const int sum = bd + last;
        const int h = sum >> 1;
        bd = (sum & 1) ? (h + (h & 1)) : h;
        if (last != qout) res[last] = 0;
      }
      if (bd != qout) res[bd] = 1;
      last = bd;
    }
  }
  if (tid == 0 && n > 0) res[inL[nch]] = 1;
  __syncthreads();

  for (int j = tid; j < TT; j += 1024) {
    if (wbuf[j] != 1) continue;
    const int lo = (j - REF_GAP_ < 0) ? 0 : j - REF_GAP_;
    const int hi = (j + REF_GAP_ - 1 > TT - 1) ? TT - 1 : j + REF_GAP_ - 1;
    int seg = 0;
    for (int w = lo; w <= hi; w++) seg += res[w];
    if (seg == 0) {
      res[j] = 1;
    } else if (seg == 1) {
      if (res[j] != 1) {
        for (int w = lo; w <= hi; w++) res[w] = (int)wbuf[w];
      }
    } else {
      int zidx = -1;
      for (int k = 1; k <= REF_GAP_; k++) {
        const int li = (j - k < 0) ? 0 : j - k;
        const int ri = (j + k > TT - 1) ? TT - 1 : j + k;
        if (res[li] == 1 && wbuf[li] != 1) { zidx = li; break; }
        if (res[ri] == 1 && wbuf[ri] != 1) { zidx = ri; break; }
      }
      if (zidx >= 0) res[zidx] = 0;
      res[j] = 1;
    }
  }
  __syncthreads();

  const int L = L_sh;
  for (int t4 = tid; t4 < TT / 4; t4 += 1024) {
    const int4 r4 = *reinterpret_cast<const int4*>(&res[t4 * 4]);
    const int t = t4 * 4;
    float4 o;
    o.x = (t + 0 >= 1 && t + 0 < L - 1) ? (float)r4.x : 0.f;
    o.y = (t + 1 >= 1 && t + 1 < L - 1) ? (float)r4.y : 0.f;
    o.z = (t + 2 >= 1 && t + 2 < L - 1) ? (float)r4.z : 0.f;
    o.w = (t + 3 >= 1 && t + 3 < L - 1) ? (float)r4.w : 0.f;
    *reinterpret_cast<float4*>(&out2[(size_t)b * TT + t]) = o;
  }
}

extern "C" void kernel_launch(void* const* d_in, const int* in_sizes, int n_in,
                              void* d_out, int out_size, void* d_ws, size_t ws_size,
                              hipStream_t stream) {
  const float* feat        = (const float*)d_in[0];
  const int*   word_bd     = (const int*)d_in[1];
  const float* non_padding = (const float*)d_in[2];
  const float* W           = (const float*)d_in[3];
  const float* bias        = (const float*)d_in[4];

  float* out  = (float*)d_out;
  float* out0 = out;
  float* out1 = out + (size_t)NB * TT;
  float* out2 = out + (size_t)NB * TT + (size_t)NB * TT * (CC - 1);

  hipLaunchKernelGGL(gemm_mfma, dim3(NGRID), dim3(512), 0, stream,
                     feat, W, bias, out0, out1);
  hipLaunchKernelGGL(phase_kernel, dim3(NB), dim3(1024), 0, stream,
                     out0, word_bd, non_padding, out2);
}